// Round 8
// baseline (48349.390 us; speedup 1.0000x reference)
//
#include <hip/hip_runtime.h>
#include <hip/hip_bf16.h>

#define T_SEQ 10240
#define GRU_W 8

typedef short bf16x8 __attribute__((ext_vector_type(8)));
typedef float f32x4 __attribute__((ext_vector_type(4)));

__device__ __forceinline__ float bf2f(unsigned short u) {
    return __uint_as_float(((unsigned int)u) << 16);
}

// ---------------- mel upsampling: fused repeat(scale) + SAME avg-conv ----------------
__global__ void upsample_kernel(const float* __restrict__ in, float* __restrict__ out,
                                const float* __restrict__ wk,
                                int B, int Tin, int Tout, int shift, int taps)
{
    int idx = blockIdx.x * blockDim.x + threadIdx.x;
    int total = B * Tout * 80;
    if (idx >= total) return;
    int m = idx % 80;
    int r = idx / 80;
    int t = r % Tout;
    int b = r / Tout;
    int s = taps >> 1;
    float acc = 0.f;
    for (int d = -s; d <= s; ++d) {
        int i = t + d;
        if (i >= 0 && i < Tout)
            acc += in[((size_t)b * Tin + (i >> shift)) * 80 + m] * wk[d + s];
    }
    out[idx] = acc;
}

// ---------------- conditioning net: conv0 (VALID, k=5) + BN + relu ----------------
__global__ __launch_bounds__(128) void conv0_kernel(
    const float* __restrict__ mels, const float* __restrict__ w,
    const float* __restrict__ g, const float* __restrict__ b,
    const float* __restrict__ m_, const float* __restrict__ v_,
    float* __restrict__ a)
{
    __shared__ float xin[400];
    int bt = blockIdx.x;              // 0..159
    int bb = bt / 40, t = bt % 40;
    int c = threadIdx.x;
    for (int idx = c; idx < 400; idx += 128)
        xin[idx] = mels[((size_t)bb * 44 + t + idx / 80) * 80 + (idx % 80)];
    __syncthreads();
    float s = 0.f;
    for (int q = 0; q < 400; ++q) s += xin[q] * w[q * 128 + c];
    s = (s - m_[c]) * rsqrtf(v_[c] + 1e-3f) * g[c] + b[c];
    a[bt * 128 + c] = fmaxf(s, 0.f);
}

// ---------------- one residual block ----------------
__global__ __launch_bounds__(128) void resblock_kernel(
    const float* __restrict__ W1, const float* __restrict__ W2,
    const float* __restrict__ g1, const float* __restrict__ b1,
    const float* __restrict__ m1, const float* __restrict__ v1,
    const float* __restrict__ g2, const float* __restrict__ b2,
    const float* __restrict__ m2, const float* __restrict__ v2,
    float* __restrict__ a)
{
    __shared__ float ain[128], y1[128];
    int tok = blockIdx.x;
    int c = threadIdx.x;
    ain[c] = a[tok * 128 + c];
    __syncthreads();
    float s = 0.f;
    #pragma unroll 8
    for (int k = 0; k < 128; ++k) s += ain[k] * W1[k * 128 + c];
    s = (s - m1[c]) * rsqrtf(v1[c] + 1e-3f) * g1[c] + b1[c];
    y1[c] = fmaxf(s, 0.f);
    __syncthreads();
    float s2 = 0.f;
    #pragma unroll 8
    for (int k = 0; k < 128; ++k) s2 += y1[k] * W2[k * 128 + c];
    s2 = (s2 - m2[c]) * rsqrtf(v2[c] + 1e-3f) * g2[c] + b2[c];
    a[tok * 128 + c] = ain[c] + s2;
}

// ---------------- cond out matmul ----------------
__global__ __launch_bounds__(128) void outmat_kernel(
    const float* __restrict__ W, const float* __restrict__ bias,
    const float* __restrict__ a, float* __restrict__ out)
{
    __shared__ float ain[128];
    int tok = blockIdx.x;
    int c = threadIdx.x;
    ain[c] = a[tok * 128 + c];
    __syncthreads();
    float s = 0.f;
    #pragma unroll 8
    for (int k = 0; k < 128; ++k) s += ain[k] * W[k * 128 + c];
    out[tok * 128 + c] = s + bias[c];
}

// ---------------- big fused GEMM (unchanged) ----------------
__device__ __forceinline__ float fetchA(int mode, int row, int k, int K,
    const float* audio, const float* melsup, const float* cond, const float* xA)
{
    if (k >= K) return 0.f;
    int b = row / T_SEQ;
    int t = row - b * T_SEQ;
    if (mode == 0) {
        if (k == 0) return audio[(size_t)b * (T_SEQ + 1) + t];
        if (k < 81) return melsup[((size_t)b * 11264 + 512 + t) * 80 + (k - 1)];
        return cond[((size_t)b * 40 + (t >> 8)) * 128 + (k - 81)];
    }
    if (k < 512) return xA[(size_t)row * 512 + k];
    int co = (mode == 2) ? 32 : (mode == 3) ? 64 : 96;
    return cond[((size_t)b * 40 + (t >> 8)) * 128 + co + (k - 512)];
}

__global__ __launch_bounds__(256) void gemm_big(
    int mode, int N, int K,
    const float* __restrict__ W, const float* __restrict__ bias1,
    const float* __restrict__ bias2,
    const float* __restrict__ audio, const float* __restrict__ melsup,
    const float* __restrict__ cond, const float* __restrict__ xA,
    const float* __restrict__ resid, float* __restrict__ outF,
    __hip_bfloat16* __restrict__ outB)
{
    __shared__ float As[16][68];
    __shared__ float Bs[16][68];
    const int tid = threadIdx.x;
    const int row0 = blockIdx.y * 64;
    const int col0 = blockIdx.x * 64;
    const int tx = tid & 15, ty = tid >> 4;
    float acc[4][4] = {};
    const int nkt = (K + 15) >> 4;
    for (int kt = 0; kt < nkt; ++kt) {
        const int kb = kt << 4;
        #pragma unroll
        for (int l = 0; l < 4; ++l) {
            int k = (tid >> 6) + l * 4;
            int m = tid & 63;
            float bv = 0.f;
            if (kb + k < K) bv = W[(size_t)(kb + k) * N + col0 + m];
            Bs[k][m] = bv;
        }
        if (mode != 0) {
            int m = tid >> 2, kq = tid & 3;
            int row = row0 + m;
            int k = kb + kq * 4;
            if (k + 3 < 512) {
                float4 v = *reinterpret_cast<const float4*>(xA + (size_t)row * 512 + k);
                As[kq * 4 + 0][m] = v.x; As[kq * 4 + 1][m] = v.y;
                As[kq * 4 + 2][m] = v.z; As[kq * 4 + 3][m] = v.w;
            } else {
                #pragma unroll
                for (int i = 0; i < 4; ++i)
                    As[kq * 4 + i][m] = fetchA(mode, row, k + i, K, audio, melsup, cond, xA);
            }
        } else {
            #pragma unroll
            for (int l = 0; l < 4; ++l) {
                int k = (tid >> 6) + l * 4;
                int m = tid & 63;
                As[k][m] = fetchA(0, row0 + m, kb + k, K, audio, melsup, cond, xA);
            }
        }
        __syncthreads();
        #pragma unroll
        for (int k = 0; k < 16; ++k) {
            float a0 = As[k][(ty << 2) + 0], a1 = As[k][(ty << 2) + 1];
            float a2 = As[k][(ty << 2) + 2], a3 = As[k][(ty << 2) + 3];
            float b0 = Bs[k][(tx << 2) + 0], b1 = Bs[k][(tx << 2) + 1];
            float b2 = Bs[k][(tx << 2) + 2], b3 = Bs[k][(tx << 2) + 3];
            acc[0][0] += a0 * b0; acc[0][1] += a0 * b1; acc[0][2] += a0 * b2; acc[0][3] += a0 * b3;
            acc[1][0] += a1 * b0; acc[1][1] += a1 * b1; acc[1][2] += a1 * b2; acc[1][3] += a1 * b3;
            acc[2][0] += a2 * b0; acc[2][1] += a2 * b1; acc[2][2] += a2 * b2; acc[2][3] += a2 * b3;
            acc[3][0] += a3 * b0; acc[3][1] += a3 * b1; acc[3][2] += a3 * b2; acc[3][3] += a3 * b3;
        }
        __syncthreads();
    }
    #pragma unroll
    for (int i = 0; i < 4; ++i) {
        int row = row0 + (ty << 2) + i;
        #pragma unroll
        for (int jt = 0; jt < 4; ++jt) {
            int col = col0 + (tx << 2) + jt;
            float v = acc[i][jt] + bias1[col];
            if (bias2 && col < 1024) v += bias2[col];
            if (mode == 0) {
                outF[(size_t)row * N + col] = v;
            } else if (mode <= 2) {
                outB[(size_t)row * 1536 + col] = __float2bfloat16(v);
            } else {
                v = fmaxf(v, 0.f) + resid[(size_t)row * 512 + col];
                outF[(size_t)row * 512 + col] = v;
            }
        }
    }
}

// ---------------- pack Wh (512,1536) f32 -> per-wave all-3-gate MFMA B-fragments ----------------
// frag id = (((wg*4 + w)*3 + g)*16 + kt)*64 + l
// n = g*512 + wg*64 + w*16 + (l&15) ; k = kt*32 + (l>>4)*8 + i
__global__ __launch_bounds__(256) void pack_wh_kernel(const float* __restrict__ Wh,
                                                      unsigned short* __restrict__ out)
{
    int gid = blockIdx.x * 256 + threadIdx.x;     // < 98304
    int l = gid & 63;
    int idx = gid >> 6;
    int kt = idx & 15; idx >>= 4;
    int g = idx % 3;
    int ww = idx / 3;                              // wg*4 + w
    int wg = ww >> 2, w = ww & 3;
    int n = g * 512 + wg * 64 + w * 16 + (l & 15);
    int k0 = kt * 32 + (l >> 4) * 8;
    unsigned short* dst = out + (size_t)gid * 8;
    #pragma unroll
    for (int i = 0; i < 8; ++i) {
        __hip_bfloat16 hv = __float2bfloat16(Wh[(size_t)(k0 + i) * 1536 + n]);
        dst[i] = *reinterpret_cast<unsigned short*>(&hv);
    }
}

// ---------------- 8-WG MFMA GRU, 1 barrier/step ----------------
// 8 WGs x 256 threads (4 waves). Wave w owns units [wg*64+w*16, +16): holds
// wf[3 gates][16 kt] B-fragments = 192 VGPR (1 wave/SIMD, cap 512). After
// MFMA, lanes 0-15 hold az/ar/ah for all 4 batches in registers -> gates
// in-wave (no acc_sh, no 2nd barrier). Gate inputs xp/xv prefetched into
// registers one step ahead (no LDS staging, no HBM on critical path).
// h_sh double-buffered (32KB) -> single __syncthreads per step.
// Cross-WG h: {tag16|bf16} 4B relaxed agent atomics, ping-pong buffers.
__global__ __launch_bounds__(256, 1) void gru_mfma8(
    const unsigned short* __restrict__ wpack,   // 8*4*3*16*64*8 bf16
    const float* __restrict__ bh,               // (1536); [1024:1536) used
    const __hip_bfloat16* __restrict__ xp,      // (4*T,1536) x@Wx+bx (+bh z/r)
    float* __restrict__ xio,                    // (4*T,512) in: x, out: x+h
    unsigned int* __restrict__ hpair,           // [2][4][512] u32, memset 0
    int T)
{
    __shared__ alignas(16) unsigned short h_sh[2][16 * 512];   // 32 KB

    const int tid = threadIdx.x;
    const int wg = blockIdx.x;
    const int w = tid >> 6;
    const int l = tid & 63;

    // ---- weights into registers (static indices) ----
    bf16x8 wf[3][16];
    {
        const bf16x8* wp = reinterpret_cast<const bf16x8*>(wpack);
        const int wbase = (wg * 4 + w) * 3 * 1024;
        #pragma unroll
        for (int g = 0; g < 3; ++g)
            #pragma unroll
            for (int kt = 0; kt < 16; ++kt)
                wf[g][kt] = wp[wbase + (g * 16 + kt) * 64 + l];
    }

    // ---- zero both h_sh buffers (pad rows 4-15 stay zero) ----
    {
        uint4* z = reinterpret_cast<uint4*>(&h_sh[0][0]);
        #pragma unroll
        for (int i = 0; i < 8; ++i) z[tid + 256 * i] = make_uint4(0, 0, 0, 0);
    }

    const int j = wg * 64 + w * 16 + (l & 15);   // owned unit (lanes 0-15)
    const float bhh = bh[1024 + j];
    float hprev[4] = {0.f, 0.f, 0.f, 0.f};
    float xz_c[4], xr_c[4], xh_c[4], xv_c[4];
    if (l < 16) {
        #pragma unroll
        for (int b = 0; b < 4; ++b) {
            const size_t rb = (size_t)b * T;
            xz_c[b] = bf2f(*reinterpret_cast<const unsigned short*>(xp + rb * 1536 + j));
            xr_c[b] = bf2f(*reinterpret_cast<const unsigned short*>(xp + rb * 1536 + 512 + j));
            xh_c[b] = bf2f(*reinterpret_cast<const unsigned short*>(xp + rb * 1536 + 1024 + j));
            xv_c[b] = xio[rb * 512 + j];
        }
    }
    __syncthreads();   // zero-init complete before first poll writes

    const unsigned long long* hp64 = reinterpret_cast<const unsigned long long*>(hpair);
    const int pb = tid >> 6;                        // polled batch row
    const int pchunk = (tid & 63) ^ (pb & 7);       // swizzled 16B chunk

    for (int t = 0; t < T; ++t) {
        const int cur = t & 1, nxt = cur ^ 1;

        // ---- poll own 8 pairs (4 independent 8B loads), sleep-throttled ----
        const unsigned long long* src = hp64 + (size_t)cur * 1024 + tid * 4;
        const unsigned tg = (unsigned)t & 0xffffu;
        unsigned long long u0 = __hip_atomic_load(src + 0, __ATOMIC_RELAXED, __HIP_MEMORY_SCOPE_AGENT);
        unsigned long long u1 = __hip_atomic_load(src + 1, __ATOMIC_RELAXED, __HIP_MEMORY_SCOPE_AGENT);
        unsigned long long u2 = __hip_atomic_load(src + 2, __ATOMIC_RELAXED, __HIP_MEMORY_SCOPE_AGENT);
        unsigned long long u3 = __hip_atomic_load(src + 3, __ATOMIC_RELAXED, __HIP_MEMORY_SCOPE_AGENT);
        while ((((unsigned)(u0 >> 16) & 0xffffu) != tg) | ((unsigned)(u0 >> 48) != tg) |
               (((unsigned)(u1 >> 16) & 0xffffu) != tg) | ((unsigned)(u1 >> 48) != tg) |
               (((unsigned)(u2 >> 16) & 0xffffu) != tg) | ((unsigned)(u2 >> 48) != tg) |
               (((unsigned)(u3 >> 16) & 0xffffu) != tg) | ((unsigned)(u3 >> 48) != tg)) {
            __builtin_amdgcn_s_sleep(1);
            u0 = __hip_atomic_load(src + 0, __ATOMIC_RELAXED, __HIP_MEMORY_SCOPE_AGENT);
            u1 = __hip_atomic_load(src + 1, __ATOMIC_RELAXED, __HIP_MEMORY_SCOPE_AGENT);
            u2 = __hip_atomic_load(src + 2, __ATOMIC_RELAXED, __HIP_MEMORY_SCOPE_AGENT);
            u3 = __hip_atomic_load(src + 3, __ATOMIC_RELAXED, __HIP_MEMORY_SCOPE_AGENT);
        }
        // 8 bf16 -> one swizzled 16B ds_write into h_sh[cur]
        {
            uint4 wv;
            wv.x = (unsigned)(u0 & 0xffffull) | ((unsigned)((u0 >> 32) & 0xffffull) << 16);
            wv.y = (unsigned)(u1 & 0xffffull) | ((unsigned)((u1 >> 32) & 0xffffull) << 16);
            wv.z = (unsigned)(u2 & 0xffffull) | ((unsigned)((u2 >> 32) & 0xffffull) << 16);
            wv.w = (unsigned)(u3 & 0xffffull) | ((unsigned)((u3 >> 32) & 0xffffull) << 16);
            *reinterpret_cast<uint4*>(
                reinterpret_cast<char*>(&h_sh[cur][0]) + pb * 1024 + pchunk * 16) = wv;
        }
        __syncthreads();   // the ONE barrier: h_sh[cur] ready

        // ---- MFMA: A = h(16x512 swizzled), B = wf[gate][kt]; 48 MFMA/wave ----
        f32x4 acc0 = {0, 0, 0, 0}, acc1 = {0, 0, 0, 0}, acc2 = {0, 0, 0, 0};
        const int rb = l & 15, q = l >> 4;
        const char* hb = reinterpret_cast<const char*>(&h_sh[cur][0]);
        #pragma unroll
        for (int kt = 0; kt < 16; ++kt) {
            bf16x8 afr = *reinterpret_cast<const bf16x8*>(
                hb + rb * 1024 + ((((kt * 4 + q) ^ (rb & 7))) << 4));
            acc0 = __builtin_amdgcn_mfma_f32_16x16x32_bf16(afr, wf[0][kt], acc0, 0, 0, 0);
            acc1 = __builtin_amdgcn_mfma_f32_16x16x32_bf16(afr, wf[1][kt], acc1, 0, 0, 0);
            acc2 = __builtin_amdgcn_mfma_f32_16x16x32_bf16(afr, wf[2][kt], acc2, 0, 0, 0);
        }

        // ---- gates in-wave: lanes 0-15 hold all 4 batches of own unit ----
        if (l < 16) {
            float hn[4];
            #pragma unroll
            for (int b = 0; b < 4; ++b) {
                float z = 1.f / (1.f + __expf(-(xz_c[b] + acc0[b])));
                float r = 1.f / (1.f + __expf(-(xr_c[b] + acc1[b])));
                float e2 = __expf(-2.f * (xh_c[b] + r * (acc2[b] + bhh)));
                float hh = (1.f - e2) / (1.f + e2);
                hn[b] = z * hprev[b] + (1.f - z) * hh;
                hprev[b] = hn[b];
            }
            if (t + 1 < T) {
                const unsigned ptag = (unsigned)((t + 1) & 0xffff) << 16;
                #pragma unroll
                for (int b = 0; b < 4; ++b) {
                    __hip_bfloat16 hb16 = __float2bfloat16(hn[b]);
                    __hip_atomic_store(hpair + (size_t)nxt * 2048 + b * 512 + j,
                                       ptag | (unsigned)*reinterpret_cast<unsigned short*>(&hb16),
                                       __ATOMIC_RELAXED, __HIP_MEMORY_SCOPE_AGENT);
                }
            }
            #pragma unroll
            for (int b = 0; b < 4; ++b)
                xio[((size_t)b * T + t) * 512 + j] = xv_c[b] + hn[b];
            // prefetch t+1 gate inputs (full step of latency to cover)
            if (t + 1 < T) {
                #pragma unroll
                for (int b = 0; b < 4; ++b) {
                    const size_t rb2 = (size_t)b * T + t + 1;
                    xz_c[b] = bf2f(*reinterpret_cast<const unsigned short*>(xp + rb2 * 1536 + j));
                    xr_c[b] = bf2f(*reinterpret_cast<const unsigned short*>(xp + rb2 * 1536 + 512 + j));
                    xh_c[b] = bf2f(*reinterpret_cast<const unsigned short*>(xp + rb2 * 1536 + 1024 + j));
                    xv_c[b] = xio[rb2 * 512 + j];
                }
            }
        }
        // no 2nd barrier: h_sh double-buffered; barrier chain orders reuse
    }
}

// ---------------- final projection ----------------
__global__ __launch_bounds__(256) void wp_kernel(
    const float* __restrict__ x, const float* __restrict__ Wp,
    const float* __restrict__ bp, float* __restrict__ out)
{
    int r = threadIdx.x >> 5, c = threadIdx.x & 31;
    size_t row = (size_t)blockIdx.x * 8 + r;
    if (c >= 30) return;
    const float* xr = x + row * 512;
    float acc = 0.f;
    #pragma unroll 8
    for (int k = 0; k < 512; ++k) acc += xr[k] * Wp[k * 30 + c];
    out[row * 30 + c] = acc + bp[c];
}

extern "C" void kernel_launch(void* const* d_in, const int* in_sizes, int n_in,
                              void* d_out, int out_size, void* d_ws, size_t ws_size,
                              hipStream_t stream)
{
    const float* audios = (const float*)d_in[0];
    const float* mels   = (const float*)d_in[1];
    const float* w_mel0 = (const float*)d_in[2];
    const float* w_mel1 = (const float*)d_in[3];
    const float* w_mel2 = (const float*)d_in[4];
    const float* conv0w = (const float*)d_in[5];
    const float* bn0g = (const float*)d_in[6];
    const float* bn0b = (const float*)d_in[7];
    const float* bn0m = (const float*)d_in[8];
    const float* bn0v = (const float*)d_in[9];
    const float* r_w1   = (const float*)d_in[10];
    const float* r_bn1g = (const float*)d_in[11];
    const float* r_bn1b = (const float*)d_in[12];
    const float* r_bn1m = (const float*)d_in[13];
    const float* r_bn1v = (const float*)d_in[14];
    const float* r_w2   = (const float*)d_in[15];
    const float* r_bn2g = (const float*)d_in[16];
    const float* r_bn2b = (const float*)d_in[17];
    const float* r_bn2m = (const float*)d_in[18];
    const float* r_bn2v = (const float*)d_in[19];
    const float* mr_out_w = (const float*)d_in[20];
    const float* mr_out_b = (const float*)d_in[21];
    const float* Wi = (const float*)d_in[22];
    const float* bi = (const float*)d_in[23];
    const float* Wx0 = (const float*)d_in[24];
    const float* Wh0 = (const float*)d_in[25];
    const float* bx0 = (const float*)d_in[26];
    const float* bh0 = (const float*)d_in[27];
    const float* Wx1 = (const float*)d_in[28];
    const float* Wh1 = (const float*)d_in[29];
    const float* bx1 = (const float*)d_in[30];
    const float* bh1 = (const float*)d_in[31];
    const float* Wd0 = (const float*)d_in[32];
    const float* bd0 = (const float*)d_in[33];
    const float* Wd1 = (const float*)d_in[34];
    const float* bd1 = (const float*)d_in[35];
    const float* Wp = (const float*)d_in[36];
    const float* bp = (const float*)d_in[37];

    char* ws = (char*)d_ws;
    size_t off = 0;
    auto alloc = [&](size_t n) { size_t r = off; off += (n + 255) & ~(size_t)255; return r; };
    const size_t M = 4 * (size_t)T_SEQ;                      // 40960
    size_t xp_off = alloc(M * 1536 * 2);                     // bf16 xp; reused as f32 x3
    size_t x_off  = alloc(M * 512 * 4);                      // f32 x
    size_t s1_off = alloc((size_t)4 * 176 * 80 * 4);
    size_t s2_off = alloc((size_t)4 * 1408 * 80 * 4);
    size_t s3_off = alloc((size_t)4 * 11264 * 80 * 4);
    size_t ca_off = alloc((size_t)160 * 128 * 4);
    size_t cf_off = alloc((size_t)160 * 128 * 4);
    size_t wp0_off = alloc((size_t)98304 * 8 * 2);           // packed Wh0 (1.5MB)
    size_t wp1_off = alloc((size_t)98304 * 8 * 2);           // packed Wh1 (1.5MB)
    size_t hp_off  = alloc(2 * 2048 * 4);                    // h pair buffers (16KB)

    __hip_bfloat16* xp = (__hip_bfloat16*)(ws + xp_off);
    float* x3   = (float*)(ws + xp_off);
    float* xbuf = (float*)(ws + x_off);
    float* st1  = (float*)(ws + s1_off);
    float* st2  = (float*)(ws + s2_off);
    float* st3  = (float*)(ws + s3_off);
    float* conda = (float*)(ws + ca_off);
    float* condf = (float*)(ws + cf_off);
    unsigned short* wpack0 = (unsigned short*)(ws + wp0_off);
    unsigned short* wpack1 = (unsigned short*)(ws + wp1_off);
    unsigned int* hpair = (unsigned int*)(ws + hp_off);
    float* outp = (float*)d_out;

    // 0: pack recurrent weights into MFMA fragment order (bf16)
    pack_wh_kernel<<<384, 256, 0, stream>>>(Wh0, wpack0);
    pack_wh_kernel<<<384, 256, 0, stream>>>(Wh1, wpack1);

    // 1-3: mel upsampling
    {
        int tot1 = 4 * 176 * 80;
        upsample_kernel<<<(tot1 + 255) / 256, 256, 0, stream>>>(mels, st1, w_mel0, 4, 44, 176, 2, 9);
        int tot2 = 4 * 1408 * 80;
        upsample_kernel<<<(tot2 + 255) / 256, 256, 0, stream>>>(st1, st2, w_mel1, 4, 176, 1408, 3, 17);
        int tot3 = 4 * 11264 * 80;
        upsample_kernel<<<(tot3 + 255) / 256, 256, 0, stream>>>(st2, st3, w_mel2, 4, 1408, 11264, 3, 17);
    }
    // 4-6: conditioning net
    conv0_kernel<<<160, 128, 0, stream>>>(mels, conv0w, bn0g, bn0b, bn0m, bn0v, conda);
    for (int i = 0; i < 10; ++i) {
        resblock_kernel<<<160, 128, 0, stream>>>(
            r_w1 + (size_t)i * 128 * 128, r_w2 + (size_t)i * 128 * 128,
            r_bn1g + i * 128, r_bn1b + i * 128, r_bn1m + i * 128, r_bn1v + i * 128,
            r_bn2g + i * 128, r_bn2b + i * 128, r_bn2m + i * 128, r_bn2v + i * 128,
            conda);
    }
    outmat_kernel<<<160, 128, 0, stream>>>(mr_out_w, mr_out_b, conda, condf);

    dim3 blk(256);
    // 7: x = concat(audio, mels_up, a0) @ Wi + bi
    gemm_big<<<dim3(8, 640), blk, 0, stream>>>(0, 512, 113, Wi, bi, nullptr,
        audios, st3, condf, nullptr, nullptr, xbuf, nullptr);
    // 8: xp0 = x @ Wx0 + bx0 (+bh0 z/r)
    gemm_big<<<dim3(24, 640), blk, 0, stream>>>(1, 1536, 512, Wx0, bx0, bh0,
        nullptr, nullptr, condf, xbuf, nullptr, nullptr, xp);
    // 9: GRU0
    hipMemsetAsync(ws + hp_off, 0, 2 * 2048 * 4, stream);
    gru_mfma8<<<GRU_W, 256, 0, stream>>>(wpack0, bh0, xp, xbuf, hpair, T_SEQ);
    // 10: xp1 = concat(x1, a1) @ Wx1 + bx1 (+bh1 z/r)
    gemm_big<<<dim3(24, 640), blk, 0, stream>>>(2, 1536, 544, Wx1, bx1, bh1,
        nullptr, nullptr, condf, xbuf, nullptr, nullptr, xp);
    // 11: GRU1
    hipMemsetAsync(ws + hp_off, 0, 2 * 2048 * 4, stream);
    gru_mfma8<<<GRU_W, 256, 0, stream>>>(wpack1, bh1, xp, xbuf, hpair, T_SEQ);
    // 12: x3 = relu(concat(x2, a2) @ Wd0 + bd0) + x2
    gemm_big<<<dim3(8, 640), blk, 0, stream>>>(3, 512, 544, Wd0, bd0, nullptr,
        nullptr, nullptr, condf, xbuf, xbuf, x3, nullptr);
    // 13: x4 = relu(concat(x3, a3) @ Wd1 + bd1) + x3
    gemm_big<<<dim3(8, 640), blk, 0, stream>>>(4, 512, 544, Wd1, bd1, nullptr,
        nullptr, nullptr, condf, x3, x3, xbuf, nullptr);
    // 14: logits
    wp_kernel<<<5120, 256, 0, stream>>>(xbuf, Wp, bp, outp);
}